// Round 7
// baseline (279.421 us; speedup 1.0000x reference)
//
#include <hip/hip_runtime.h>
#include <math.h>

#define QN 21760
#define MTOT 43520      // = 340 * 128
#define SZBQC 11141120  // MTOT*256

typedef __attribute__((ext_vector_type(8))) short bf16x8;
typedef __attribute__((ext_vector_type(4))) float f32x4;

__device__ inline ushort f2bf(float f) {
  union { float f; uint u; } v; v.f = f;
  return (ushort)((v.u + 0x7FFFu + ((v.u >> 16) & 1u)) >> 16);
}
__device__ inline uint pk2(float lo, float hi) { return (uint)f2bf(lo) | ((uint)f2bf(hi) << 16); }

__device__ inline void g2l(const ushort* g, ushort* l) {
  __builtin_amdgcn_global_load_lds(
      (const __attribute__((address_space(1))) void*)g,
      (__attribute__((address_space(3))) void*)l, 16, 0, 0);
}

// ---------------- weight prep + A precast ----------------
// blocks <896: weight transpose/cast (unchanged).
// blocks >=896 (only when workspace allows): stream value|query f32 -> bf16
// into abf ([value rows | query rows], 256 cols) so gemm_in can g2l A.
__global__ __launch_bounds__(256) void prep_weights(
    const float* __restrict__ Wv, const float* __restrict__ Wout,
    const float* __restrict__ Woff, const float* __restrict__ Wattn,
    const float* __restrict__ boff, const float* __restrict__ battn,
    const float* __restrict__ value, const float* __restrict__ query,
    ushort* __restrict__ wv_t, ushort* __restrict__ wout_t,
    ushort* __restrict__ wol_t, float* __restrict__ biasf,
    ushort* __restrict__ abf) {
  int bidx = blockIdx.x, t = threadIdx.x;
  if (bidx < 256) {
    int idx = bidx * 256 + t; int n = idx >> 8, k = idx & 255;
    wv_t[idx] = f2bf(Wv[(size_t)k * 256 + n]);
  } else if (bidx < 512) {
    int idx = (bidx - 256) * 256 + t; int n = idx >> 8, k = idx & 255;
    wout_t[idx] = f2bf(Wout[(size_t)k * 256 + n]);
  } else if (bidx < 896) {
    int idx = (bidx - 512) * 256 + t; int n = idx >> 8, k = idx & 255;
    float v = (n < 256) ? Woff[(size_t)k * 256 + n] : Wattn[(size_t)k * 128 + (n - 256)];
    wol_t[idx] = f2bf(v);
    if (idx < 384) biasf[idx] = (idx < 256) ? boff[idx] : battn[idx - 256];
  } else {
    // precast: 8 f32 -> 8 bf16 per thread; no value/query straddle (divisible)
    int idx = (bidx - 896) * 2048 + t * 8;
    const float* s = (idx < SZBQC) ? (value + idx) : (query + (idx - SZBQC));
    float4 a = *(const float4*)s;
    float4 c = *(const float4*)(s + 4);
    uint4 o;
    o.x = pk2(a.x, a.y); o.y = pk2(a.z, a.w);
    o.z = pk2(c.x, c.y); o.w = pk2(c.z, c.w);
    *(uint4*)&abf[idx] = o;
  }
}

// ---- XOR-swizzled LDS tile: 128 rows x 32 ushort; 16B chunk c of row r
// lives at physical chunk c ^ ((r>>1)&3). Frag reads are conflict-free. ----

// ---------------- fused input GEMM v2: all-g2l (A pre-cast bf16) ----------------
// grid (340,5): by<2 -> val panels; by>=2 -> offlog panels. Staging loop is
// identical to gemm_out's (pure global_load_lds, zero cast VALU).
__global__ __launch_bounds__(256) void gemm_in_g2l(
    const ushort* __restrict__ abf,
    const ushort* __restrict__ Wv, const ushort* __restrict__ Wol,
    const float* __restrict__ bv, const float* __restrict__ bol,
    ushort* __restrict__ val_out, float* __restrict__ offlog) {
  __shared__ ushort As[2][4096];
  __shared__ ushort Bs[2][4096];
  const int t = threadIdx.x, wave = t >> 6, lane = t & 63;
  const int bx = blockIdx.y, bm = blockIdx.x * 128;
  const bool isVal = bx < 2;
  const ushort* A  = abf + (isVal ? 0 : SZBQC);
  const ushort* Bt = isVal ? (Wv + (size_t)bx * 128 * 256)
                           : (Wol + (size_t)(bx - 2) * 128 * 256);
  const int wm = (wave >> 1) * 64, wn = (wave & 1) * 64;
  const int l15 = lane & 15, l4 = lane >> 4;
  const int pc = l4 ^ ((l15 >> 1) & 3);

  const int srow = lane >> 2;
  const int sch  = (lane & 3) ^ ((lane >> 3) & 3);
  const ushort* Ag = A + (size_t)(bm + 32 * wave + srow) * 256 + sch * 8;
  const ushort* Bg = Bt + (size_t)(32 * wave + srow) * 256 + sch * 8;
  ushort* la[2] = { &As[0][(32 * wave) * 32], &As[1][(32 * wave) * 32] };
  ushort* lb[2] = { &Bs[0][(32 * wave) * 32], &Bs[1][(32 * wave) * 32] };

  f32x4 acc[4][4];
#pragma unroll
  for (int i = 0; i < 4; ++i)
#pragma unroll
    for (int j = 0; j < 4; ++j) acc[i][j] = (f32x4){0.f, 0.f, 0.f, 0.f};

  g2l(Ag, la[0]); g2l(Ag + 16 * 256, la[0] + 16 * 32);
  g2l(Bg, lb[0]); g2l(Bg + 16 * 256, lb[0] + 16 * 32);

  for (int k = 0; k < 8; ++k) {
    __syncthreads();
    const int cur = k & 1, nxt = cur ^ 1;
    if (k < 7) {
      int k1 = (k + 1) * 32;
      g2l(Ag + k1, la[nxt]); g2l(Ag + 16 * 256 + k1, la[nxt] + 16 * 32);
      g2l(Bg + k1, lb[nxt]); g2l(Bg + 16 * 256 + k1, lb[nxt] + 16 * 32);
    }
    bf16x8 af[4], bfr[4];
#pragma unroll
    for (int mi = 0; mi < 4; ++mi)
      af[mi] = *(const bf16x8*)&As[cur][(wm + mi * 16 + l15) * 32 + pc * 8];
#pragma unroll
    for (int ni = 0; ni < 4; ++ni)
      bfr[ni] = *(const bf16x8*)&Bs[cur][(wn + ni * 16 + l15) * 32 + pc * 8];
#pragma unroll
    for (int mi = 0; mi < 4; ++mi)
#pragma unroll
      for (int ni = 0; ni < 4; ++ni)
        acc[mi][ni] = __builtin_amdgcn_mfma_f32_16x16x32_bf16(af[mi], bfr[ni], acc[mi][ni], 0, 0, 0);
  }

  if (isVal) {
    _Float16* vo = (_Float16*)val_out;
#pragma unroll
    for (int mi = 0; mi < 4; ++mi)
#pragma unroll
      for (int ni = 0; ni < 4; ++ni) {
        int col = bx * 128 + wn + ni * 16 + l15;
        float bb = bv[col];
        int hh = col >> 5, c = col & 31;
#pragma unroll
        for (int r = 0; r < 4; ++r) {
          int row = bm + wm + mi * 16 + l4 * 4 + r;
          int b = (row >= QN) ? 1 : 0;
          int vpos = row - b * QN;
          vo[((size_t)(b * 8 + hh) * QN + vpos) * 32 + c] = (_Float16)(acc[mi][ni][r] + bb);
        }
      }
  } else {
#pragma unroll
    for (int mi = 0; mi < 4; ++mi)
#pragma unroll
      for (int ni = 0; ni < 4; ++ni) {
        int col = (bx - 2) * 128 + wn + ni * 16 + l15;
        float bb = bol[col];
#pragma unroll
        for (int r = 0; r < 4; ++r) {
          int row = bm + wm + mi * 16 + l4 * 4 + r;
          offlog[(size_t)row * 384 + col] = acc[mi][ni][r] + bb;
        }
      }
  }
}

// ---------------- fallback input GEMM (cast in-loop, r6 version, 2-D grid) ----
__global__ __launch_bounds__(256) void gemm_in_cast(
    const float* __restrict__ value, const float* __restrict__ query,
    const ushort* __restrict__ Wv, const ushort* __restrict__ Wol,
    const float* __restrict__ bv, const float* __restrict__ bol,
    ushort* __restrict__ val_out, float* __restrict__ offlog) {
  __shared__ ushort As[2][4096];
  __shared__ ushort Bs[2][4096];
  const int t = threadIdx.x, wave = t >> 6, lane = t & 63;
  const int bx = blockIdx.y, bm = blockIdx.x * 128;
  const bool isVal = bx < 2;
  const float* A   = isVal ? value : query;
  const ushort* Bt = isVal ? (Wv + (size_t)bx * 128 * 256)
                           : (Wol + (size_t)(bx - 2) * 128 * 256);
  const int wm = (wave >> 1) * 64, wn = (wave & 1) * 64;
  const int l15 = lane & 15, l4 = lane >> 4;
  const int pc = l4 ^ ((l15 >> 1) & 3);

  const int srow = lane >> 2;
  const int sch  = (lane & 3) ^ ((lane >> 3) & 3);
  const ushort* Bg = Bt + (size_t)(32 * wave + srow) * 256 + sch * 8;
  ushort* lb[2] = { &Bs[0][(32 * wave) * 32], &Bs[1][(32 * wave) * 32] };

  f32x4 acc[4][4];
#pragma unroll
  for (int i = 0; i < 4; ++i)
#pragma unroll
    for (int j = 0; j < 4; ++j) acc[i][j] = (f32x4){0.f, 0.f, 0.f, 0.f};

  int arow[4], apart[4];
#pragma unroll
  for (int i = 0; i < 4; ++i) {
    int c = t + i * 256; arow[i] = c >> 3; apart[i] = c & 7;
  }

  {
    float4 pa[4];
#pragma unroll
    for (int i = 0; i < 4; ++i)
      pa[i] = *(const float4*)&A[(size_t)(bm + arow[i]) * 256 + apart[i] * 4];
    g2l(Bg, lb[0]); g2l(Bg + 16 * 256, lb[0] + 16 * 32);
#pragma unroll
    for (int i = 0; i < 4; ++i) {
      int pc16 = (apart[i] >> 1) ^ ((arow[i] >> 1) & 3);
      ushort4 hv = { f2bf(pa[i].x), f2bf(pa[i].y), f2bf(pa[i].z), f2bf(pa[i].w) };
      *(ushort4*)&As[0][arow[i] * 32 + pc16 * 8 + (apart[i] & 1) * 4] = hv;
    }
  }

  for (int k = 0; k < 8; ++k) {
    __syncthreads();
    const int cur = k & 1, nxt = cur ^ 1;
    float4 pa[4];
    if (k < 7) {
      int k1 = (k + 1) * 32;
#pragma unroll
      for (int i = 0; i < 4; ++i)
        pa[i] = *(const float4*)&A[(size_t)(bm + arow[i]) * 256 + k1 + apart[i] * 4];
      g2l(Bg + k1, lb[nxt]); g2l(Bg + 16 * 256 + k1, lb[nxt] + 16 * 32);
    }
    bf16x8 af[4], bfr[4];
#pragma unroll
    for (int mi = 0; mi < 4; ++mi)
      af[mi] = *(const bf16x8*)&As[cur][(wm + mi * 16 + l15) * 32 + pc * 8];
#pragma unroll
    for (int ni = 0; ni < 4; ++ni)
      bfr[ni] = *(const bf16x8*)&Bs[cur][(wn + ni * 16 + l15) * 32 + pc * 8];
#pragma unroll
    for (int mi = 0; mi < 4; ++mi)
#pragma unroll
      for (int ni = 0; ni < 4; ++ni)
        acc[mi][ni] = __builtin_amdgcn_mfma_f32_16x16x32_bf16(af[mi], bfr[ni], acc[mi][ni], 0, 0, 0);
    if (k < 7) {
#pragma unroll
      for (int i = 0; i < 4; ++i) {
        int pc16 = (apart[i] >> 1) ^ ((arow[i] >> 1) & 3);
        ushort4 hv = { f2bf(pa[i].x), f2bf(pa[i].y), f2bf(pa[i].z), f2bf(pa[i].w) };
        *(ushort4*)&As[nxt][arow[i] * 32 + pc16 * 8 + (apart[i] & 1) * 4] = hv;
      }
    }
  }

  if (isVal) {
    _Float16* vo = (_Float16*)val_out;
#pragma unroll
    for (int mi = 0; mi < 4; ++mi)
#pragma unroll
      for (int ni = 0; ni < 4; ++ni) {
        int col = bx * 128 + wn + ni * 16 + l15;
        float bb = bv[col];
        int hh = col >> 5, c = col & 31;
#pragma unroll
        for (int r = 0; r < 4; ++r) {
          int row = bm + wm + mi * 16 + l4 * 4 + r;
          int b = (row >= QN) ? 1 : 0;
          int vpos = row - b * QN;
          vo[((size_t)(b * 8 + hh) * QN + vpos) * 32 + c] = (_Float16)(acc[mi][ni][r] + bb);
        }
      }
  } else {
#pragma unroll
    for (int mi = 0; mi < 4; ++mi)
#pragma unroll
      for (int ni = 0; ni < 4; ++ni) {
        int col = (bx - 2) * 128 + wn + ni * 16 + l15;
        float bb = bol[col];
#pragma unroll
        for (int r = 0; r < 4; ++r) {
          int row = bm + wm + mi * 16 + l4 * 4 + r;
          offlog[(size_t)row * 384 + col] = acc[mi][ni][r] + bb;
        }
      }
  }
}

// ---------------- output GEMM (A bf16), dbuf, all-g2l, swizzled ----------------
__global__ __launch_bounds__(256) void gemm_out(
    const ushort* __restrict__ A, const ushort* __restrict__ Bt,
    const float* __restrict__ bias, float* __restrict__ C) {
  __shared__ ushort As[2][4096];
  __shared__ ushort Bs[2][4096];
  const int t = threadIdx.x, wave = t >> 6, lane = t & 63;
  const int bm = blockIdx.x * 128, bn = blockIdx.y * 128;
  const int wm = (wave >> 1) * 64, wn = (wave & 1) * 64;
  const int l15 = lane & 15, l4 = lane >> 4;
  const int pc = l4 ^ ((l15 >> 1) & 3);

  const int srow = lane >> 2;
  const int sch  = (lane & 3) ^ ((lane >> 3) & 3);
  const ushort* Ag = A + (size_t)(bm + 32 * wave + srow) * 256 + sch * 8;
  const ushort* Bg = Bt + (size_t)(bn + 32 * wave + srow) * 256 + sch * 8;
  ushort* la[2] = { &As[0][(32 * wave) * 32], &As[1][(32 * wave) * 32] };
  ushort* lb[2] = { &Bs[0][(32 * wave) * 32], &Bs[1][(32 * wave) * 32] };

  f32x4 acc[4][4];
#pragma unroll
  for (int i = 0; i < 4; ++i)
#pragma unroll
    for (int j = 0; j < 4; ++j) acc[i][j] = (f32x4){0.f, 0.f, 0.f, 0.f};

  g2l(Ag, la[0]); g2l(Ag + 16 * 256, la[0] + 16 * 32);
  g2l(Bg, lb[0]); g2l(Bg + 16 * 256, lb[0] + 16 * 32);

  for (int k = 0; k < 8; ++k) {
    __syncthreads();
    const int cur = k & 1, nxt = cur ^ 1;
    if (k < 7) {
      int k1 = (k + 1) * 32;
      g2l(Ag + k1, la[nxt]); g2l(Ag + 16 * 256 + k1, la[nxt] + 16 * 32);
      g2l(Bg + k1, lb[nxt]); g2l(Bg + 16 * 256 + k1, lb[nxt] + 16 * 32);
    }
    bf16x8 af[4], bfr[4];
#pragma unroll
    for (int mi = 0; mi < 4; ++mi)
      af[mi] = *(const bf16x8*)&As[cur][(wm + mi * 16 + l15) * 32 + pc * 8];
#pragma unroll
    for (int ni = 0; ni < 4; ++ni)
      bfr[ni] = *(const bf16x8*)&Bs[cur][(wn + ni * 16 + l15) * 32 + pc * 8];
#pragma unroll
    for (int mi = 0; mi < 4; ++mi)
#pragma unroll
      for (int ni = 0; ni < 4; ++ni)
        acc[mi][ni] = __builtin_amdgcn_mfma_f32_16x16x32_bf16(af[mi], bfr[ni], acc[mi][ni], 0, 0, 0);
  }

#pragma unroll
  for (int mi = 0; mi < 4; ++mi)
#pragma unroll
    for (int ni = 0; ni < 4; ++ni) {
      int col = bn + wn + ni * 16 + l15;
      float bb = bias[col];
#pragma unroll
      for (int r = 0; r < 4; ++r) {
        int row = bm + wm + mi * 16 + l4 * 4 + r;
        C[(size_t)row * 256 + col] = acc[mi][ni][r] + bb;
      }
    }
}

// ---------------- deformable sampling ----------------
// v5 = v4 (owner-lane de-replication, proven -14 µs) + 2-deep point pipeline:
// fully-unrolled 16-point loop, double-buffered NAMED regs (compile-time
// indices only); point j+1's 7 shfl broadcasts + 4 gathers issue BEFORE
// point j's 32 fma consume -> loads overlap consumption (T14).
__device__ inline void fmah(float* a, uint4 u, float wv) {
  union { uint4 u; _Float16 h[8]; } c; c.u = u;
#pragma unroll
  for (int i = 0; i < 8; ++i) a[i] = fmaf((float)c.h[i], wv, a[i]);
}

__global__ __launch_bounds__(256) void msda_sample(
    const ushort* __restrict__ val, const float* __restrict__ offlog,
    const float* __restrict__ ref, ushort* __restrict__ interm) {
  int h   = blockIdx.x & 7;
  int z   = blockIdx.x >> 3;          // 0..679
  int sub = threadIdx.x & 3;
  int bq  = z * 64 + (threadIdx.x >> 2);   // 680*64 = 43520
  int b   = (bq >= QN) ? 1 : 0;
  const uint sub8 = (uint)(sub * 8);
  const ushort* vb = val + (size_t)((uint)(b * 8 + h) * (uint)QN) * 32u + sub8;

  // ---- softmax, distributed: lane owns level `sub`'s 4 logits ----
  const float* lgp = offlog + (size_t)bq * 384 + 256 + h * 16;
  float4 lg = *(const float4*)(lgp + sub * 4);
  float m = fmaxf(fmaxf(lg.x, lg.y), fmaxf(lg.z, lg.w));
  m = fmaxf(m, __shfl_xor(m, 1, 64));
  m = fmaxf(m, __shfl_xor(m, 2, 64));
  float e0 = __expf(lg.x - m), e1 = __expf(lg.y - m),
        e2 = __expf(lg.z - m), e3 = __expf(lg.w - m);
  float s = e0 + e1 + e2 + e3;
  s += __shfl_xor(s, 1, 64);
  s += __shfl_xor(s, 2, 64);
  float inv = __builtin_amdgcn_rcpf(s);
  float aw[4] = { e0 * inv, e1 * inv, e2 * inv, e3 * inv };

  // ---- owned level geometry (level = sub) ----
  const int  Wl  = 128 >> sub;                       // 128,64,32,16
  const uint t16 = 65536u >> (sub + sub);
  const int  lst = (int)((65536u - t16) / 3u);       // 0,16384,20480,21504
  const float fW = (float)Wl;
  const float* offp = offlog + (size_t)bq * 384 + h * 32;
  float4 o0 = *(const float4*)(offp + sub * 8);
  float4 o1 = *(const float4*)(offp + sub * 8 + 4);
  float2 rf = *(const float2*)(ref + (size_t)bq * 8 + sub * 2);
  const float xb = rf.x * fW - 0.5f;
  const float yb = rf.y * fW - 0.5f;
  float ox[4] = { o0.x, o0.z, o1.x, o1.z };
  float oy[4] = { o0.y, o0.w, o1.y, o1.w };

  uint  pA0[4], pA1[4], pDX[4];
  float pX0[4], pX1[4], pY0[4], pY1[4];
#pragma unroll
  for (int p = 0; p < 4; ++p) {
    float x = xb + ox[p], y = yb + oy[p];
    float x0f = floorf(x), y0f = floorf(y);
    float fx = x - x0f, fy = y - y0f;
    int x0 = (int)x0f, y0 = (int)y0f;
    float a = aw[p];
    pX0[p] = ((uint)x0       < (uint)Wl) ? (1.f - fx) : 0.f;
    pX1[p] = ((uint)(x0 + 1) < (uint)Wl) ? fx         : 0.f;
    pY0[p] = (((uint)y0       < (uint)Wl) ? (1.f - fy) : 0.f) * a;
    pY1[p] = (((uint)(y0 + 1) < (uint)Wl) ? fy         : 0.f) * a;
    int xc0 = min(max(x0, 0), Wl - 1);
    int xc1 = min(max(x0 + 1, 0), Wl - 1);
    int yc0 = min(max(y0, 0), Wl - 1);
    int yc1 = min(max(y0 + 1, 0), Wl - 1);
    pA0[p] = (uint)((lst + yc0 * Wl + xc0) * 32);
    pA1[p] = (uint)((lst + yc1 * Wl + xc0) * 32);
    pDX[p] = (uint)((xc1 - xc0) * 32);
  }

  float acc[8];
#pragma unroll
  for (int i = 0; i < 8; ++i) acc[i] = 0.f;

  const int lanebase = (threadIdx.x & 63) & 60;      // lane & ~3

  uint  bA0[2], bA1[2], bDX[2];
  float bX0[2], bX1[2], bY0[2], bY1[2];
  uint4 u00[2], u01[2], u10[2], u11[2];

#define MSDA_BCAST(J, S) do {                                   \
    const int l_ = (J) >> 2, p_ = (J) & 3;                      \
    const int src_ = lanebase | l_;                             \
    bA0[S] = (uint)__shfl((int)pA0[p_], src_, 64);              \
    bA1[S] = (uint)__shfl((int)pA1[p_], src_, 64);              \
    bDX[S] = (uint)__shfl((int)pDX[p_], src_, 64);              \
    bX0[S] = __shfl(pX0[p_], src_, 64);                         \
    bX1[S] = __shfl(pX1[p_], src_, 64);                         \
    bY0[S] = __shfl(pY0[p_], src_, 64);                         \
    bY1[S] = __shfl(pY1[p_], src_, 64);                         \
  } while (0)
#define MSDA_LOAD(S) do {                                       \
    u00[S] = *(const uint4*)(vb + bA0[S]);                      \
    u01[S] = *(const uint4*)(vb + bA0[S] + bDX[S]);             \
    u10[S] = *(const uint4*)(vb + bA1[S]);                      \
    u11[S] = *(const uint4*)(vb + bA1[S] + bDX[S]);             \
  } while (0)

  MSDA_BCAST(0, 0);
  MSDA_LOAD(0);
#pragma unroll
  for (int j = 0; j < 16; ++j) {
    const int cur = j & 1, nxt = cur ^ 1;
    if (j < 15) { MSDA_BCAST(j + 1, nxt); MSDA_LOAD(nxt); }
    fmah(acc, u00[cur], bX0[cur] * bY0[cur]);
    fmah(acc, u01[cur], bX1[cur] * bY0[cur]);
    fmah(acc, u10[cur], bX0[cur] * bY1[cur]);
    fmah(acc, u11[cur], bX1[cur] * bY1[cur]);
  }
#undef MSDA_BCAST
#undef MSDA_LOAD

  uint4 o;
  o.x = pk2(acc[0], acc[1]); o.y = pk2(acc[2], acc[3]);
  o.z = pk2(acc[4], acc[5]); o.w = pk2(acc[6], acc[7]);
  *(uint4*)(interm + (size_t)bq * 256 + h * 32 + sub * 8) = o;
}

extern "C" void kernel_launch(void* const* d_in, const int* in_sizes, int n_in,
                              void* d_out, int out_size, void* d_ws, size_t ws_size,
                              hipStream_t stream) {
  const float* query = (const float*)d_in[0];
  const float* value = (const float*)d_in[1];
  const float* ref   = (const float*)d_in[2];
  const float* W_off  = (const float*)d_in[4];
  const float* b_off  = (const float*)d_in[5];
  const float* W_attn = (const float*)d_in[6];
  const float* b_attn = (const float*)d_in[7];
  const float* W_v    = (const float*)d_in[8];
  const float* b_v    = (const float*)d_in[9];
  const float* W_out  = (const float*)d_in[10];
  const float* b_out  = (const float*)d_in[11];
  float* out = (float*)d_out;

  // ---- workspace (byte offsets, 256-aligned) ----
  char* wsb = (char*)d_ws;
  ushort* ws_wv     = (ushort*)(wsb + 0);          // 131072 B
  ushort* ws_wol    = (ushort*)(wsb + 131072);     // 196608 B
  ushort* ws_wout   = (ushort*)(wsb + 327680);     // 131072 B
  float*  ws_biasf  = (float*)(wsb + 458752);      // 4096 B
  ushort* ws_val    = (ushort*)(wsb + 462848);     // 22282240 B fp16 head-split
  ushort* ws_interm = (ushort*)(wsb + 22745088);   // 22282240 B bf16 (M,256)
  float*  ws_offlog = (float*)(wsb + 45027328);    // 66846720 B f32 (M,384)
  ushort* ws_abf    = (ushort*)(wsb + 111874048);  // 44564480 B bf16 [value|query]
  size_t need_base = (size_t)45027328 + 66846720;              // ~112 MB
  size_t need_big  = need_base + 44564480;                     // ~156 MB
  if (ws_size < need_base) return;
  const bool big = (ws_size >= need_big);

  dim3 blk(256);
  prep_weights<<<dim3(big ? 11776 : 896), blk, 0, stream>>>(
      W_v, W_out, W_off, W_attn, b_off, b_attn, value, query,
      ws_wv, ws_wout, ws_wol, ws_biasf, ws_abf);
  if (big) {
    gemm_in_g2l<<<dim3(340, 5), blk, 0, stream>>>(ws_abf, ws_wv, ws_wol, b_v, ws_biasf,
                                                  ws_val, ws_offlog);
  } else {
    gemm_in_cast<<<dim3(340, 5), blk, 0, stream>>>(value, query, ws_wv, ws_wol, b_v, ws_biasf,
                                                   ws_val, ws_offlog);
  }
  msda_sample<<<dim3(5440), blk, 0, stream>>>(ws_val, ws_offlog, ref, ws_interm);
  gemm_out<<<dim3(340, 2), blk, 0, stream>>>(ws_interm, ws_wout, b_out, out);
}

// Round 8
// 267.696 us; speedup vs baseline: 1.0438x; 1.0438x over previous
//
#include <hip/hip_runtime.h>
#include <math.h>

#define QN 21760
#define MTOT 43520      // = 340 * 128
#define SZBQC 11141120  // MTOT*256

typedef __attribute__((ext_vector_type(8))) short bf16x8;
typedef __attribute__((ext_vector_type(4))) float f32x4;

__device__ inline ushort f2bf(float f) {
  union { float f; uint u; } v; v.f = f;
  return (ushort)((v.u + 0x7FFFu + ((v.u >> 16) & 1u)) >> 16);
}
__device__ inline uint pk2(float lo, float hi) { return (uint)f2bf(lo) | ((uint)f2bf(hi) << 16); }

__device__ inline void g2l(const ushort* g, ushort* l) {
  __builtin_amdgcn_global_load_lds(
      (const __attribute__((address_space(1))) void*)g,
      (__attribute__((address_space(3))) void*)l, 16, 0, 0);
}

// ---------------- weight prep ----------------
__global__ __launch_bounds__(256) void prep_weights(
    const float* __restrict__ Wv, const float* __restrict__ Wout,
    const float* __restrict__ Woff, const float* __restrict__ Wattn,
    const float* __restrict__ boff, const float* __restrict__ battn,
    ushort* __restrict__ wv_t, ushort* __restrict__ wout_t,
    ushort* __restrict__ wol_t, float* __restrict__ biasf) {
  int bidx = blockIdx.x, t = threadIdx.x;
  if (bidx < 256) {
    int idx = bidx * 256 + t; int n = idx >> 8, k = idx & 255;
    wv_t[idx] = f2bf(Wv[(size_t)k * 256 + n]);
  } else if (bidx < 512) {
    int idx = (bidx - 256) * 256 + t; int n = idx >> 8, k = idx & 255;
    wout_t[idx] = f2bf(Wout[(size_t)k * 256 + n]);
  } else {
    int idx = (bidx - 512) * 256 + t; int n = idx >> 8, k = idx & 255;
    float v = (n < 256) ? Woff[(size_t)k * 256 + n] : Wattn[(size_t)k * 128 + (n - 256)];
    wol_t[idx] = f2bf(v);
    if (idx < 384) biasf[idx] = (idx < 256) ? boff[idx] : battn[idx - 256];
  }
}

// ---- XOR-swizzled LDS tile: 128 rows x 32 ushort; 16B chunk c of row r
// lives at physical chunk c ^ ((r>>1)&3). Frag reads are conflict-free. ----

// ---------------- fused input GEMM (val + offlog), cast-in-loop ----------------
__global__ __launch_bounds__(256) void gemm_in(
    const float* __restrict__ value, const float* __restrict__ query,
    const ushort* __restrict__ Wv, const ushort* __restrict__ Wol,
    const float* __restrict__ bv, const float* __restrict__ bol,
    ushort* __restrict__ val_out, float* __restrict__ offlog) {
  __shared__ ushort As[2][4096];
  __shared__ ushort Bs[2][4096];
  const int t = threadIdx.x, wave = t >> 6, lane = t & 63;
  const int bx = blockIdx.y, bm = blockIdx.x * 128;
  const bool isVal = bx < 2;
  const float* A   = isVal ? value : query;
  const ushort* Bt = isVal ? (Wv + (size_t)bx * 128 * 256)
                           : (Wol + (size_t)(bx - 2) * 128 * 256);
  const int wm = (wave >> 1) * 64, wn = (wave & 1) * 64;
  const int l15 = lane & 15, l4 = lane >> 4;
  const int pc = l4 ^ ((l15 >> 1) & 3);              // frag-read physical chunk

  const int srow = lane >> 2;
  const int sch  = (lane & 3) ^ ((lane >> 3) & 3);
  const ushort* Bg = Bt + (size_t)(32 * wave + srow) * 256 + sch * 8;
  ushort* lb[2] = { &Bs[0][(32 * wave) * 32], &Bs[1][(32 * wave) * 32] };

  f32x4 acc[4][4];
#pragma unroll
  for (int i = 0; i < 4; ++i)
#pragma unroll
    for (int j = 0; j < 4; ++j) acc[i][j] = (f32x4){0.f, 0.f, 0.f, 0.f};

  int arow[4], apart[4];
#pragma unroll
  for (int i = 0; i < 4; ++i) {
    int c = t + i * 256; arow[i] = c >> 3; apart[i] = c & 7;
  }

  {
    float4 pa[4];
#pragma unroll
    for (int i = 0; i < 4; ++i)
      pa[i] = *(const float4*)&A[(size_t)(bm + arow[i]) * 256 + apart[i] * 4];
    g2l(Bg, lb[0]); g2l(Bg + 16 * 256, lb[0] + 16 * 32);
#pragma unroll
    for (int i = 0; i < 4; ++i) {
      int pc16 = (apart[i] >> 1) ^ ((arow[i] >> 1) & 3);
      ushort4 hv = { f2bf(pa[i].x), f2bf(pa[i].y), f2bf(pa[i].z), f2bf(pa[i].w) };
      *(ushort4*)&As[0][arow[i] * 32 + pc16 * 8 + (apart[i] & 1) * 4] = hv;
    }
  }

  for (int k = 0; k < 8; ++k) {
    __syncthreads();
    const int cur = k & 1, nxt = cur ^ 1;
    float4 pa[4];
    if (k < 7) {
      int k1 = (k + 1) * 32;
#pragma unroll
      for (int i = 0; i < 4; ++i)
        pa[i] = *(const float4*)&A[(size_t)(bm + arow[i]) * 256 + k1 + apart[i] * 4];
      g2l(Bg + k1, lb[nxt]); g2l(Bg + 16 * 256 + k1, lb[nxt] + 16 * 32);
    }
    bf16x8 af[4], bfr[4];
#pragma unroll
    for (int mi = 0; mi < 4; ++mi)
      af[mi] = *(const bf16x8*)&As[cur][(wm + mi * 16 + l15) * 32 + pc * 8];
#pragma unroll
    for (int ni = 0; ni < 4; ++ni)
      bfr[ni] = *(const bf16x8*)&Bs[cur][(wn + ni * 16 + l15) * 32 + pc * 8];
#pragma unroll
    for (int mi = 0; mi < 4; ++mi)
#pragma unroll
      for (int ni = 0; ni < 4; ++ni)
        acc[mi][ni] = __builtin_amdgcn_mfma_f32_16x16x32_bf16(af[mi], bfr[ni], acc[mi][ni], 0, 0, 0);
    if (k < 7) {
#pragma unroll
      for (int i = 0; i < 4; ++i) {
        int pc16 = (apart[i] >> 1) ^ ((arow[i] >> 1) & 3);
        ushort4 hv = { f2bf(pa[i].x), f2bf(pa[i].y), f2bf(pa[i].z), f2bf(pa[i].w) };
        *(ushort4*)&As[nxt][arow[i] * 32 + pc16 * 8 + (apart[i] & 1) * 4] = hv;
      }
    }
  }

  if (isVal) {
    _Float16* vo = (_Float16*)val_out;
#pragma unroll
    for (int mi = 0; mi < 4; ++mi)
#pragma unroll
      for (int ni = 0; ni < 4; ++ni) {
        int col = bx * 128 + wn + ni * 16 + l15;
        float bb = bv[col];
        int hh = col >> 5, c = col & 31;
#pragma unroll
        for (int r = 0; r < 4; ++r) {
          int row = bm + wm + mi * 16 + l4 * 4 + r;
          int b = (row >= QN) ? 1 : 0;
          int vpos = row - b * QN;
          vo[((size_t)(b * 8 + hh) * QN + vpos) * 32 + c] = (_Float16)(acc[mi][ni][r] + bb);
        }
      }
  } else {
#pragma unroll
    for (int mi = 0; mi < 4; ++mi)
#pragma unroll
      for (int ni = 0; ni < 4; ++ni) {
        int col = (bx - 2) * 128 + wn + ni * 16 + l15;
        float bb = bol[col];
#pragma unroll
        for (int r = 0; r < 4; ++r) {
          int row = bm + wm + mi * 16 + l4 * 4 + r;
          offlog[(size_t)row * 384 + col] = acc[mi][ni][r] + bb;
        }
      }
  }
}

// ---------------- output GEMM (A bf16), dbuf, all-g2l, swizzled ----------------
__global__ __launch_bounds__(256) void gemm_out(
    const ushort* __restrict__ A, const ushort* __restrict__ Bt,
    const float* __restrict__ bias, float* __restrict__ C) {
  __shared__ ushort As[2][4096];
  __shared__ ushort Bs[2][4096];
  const int t = threadIdx.x, wave = t >> 6, lane = t & 63;
  const int bm = blockIdx.x * 128, bn = blockIdx.y * 128;
  const int wm = (wave >> 1) * 64, wn = (wave & 1) * 64;
  const int l15 = lane & 15, l4 = lane >> 4;
  const int pc = l4 ^ ((l15 >> 1) & 3);

  const int srow = lane >> 2;
  const int sch  = (lane & 3) ^ ((lane >> 3) & 3);
  const ushort* Ag = A + (size_t)(bm + 32 * wave + srow) * 256 + sch * 8;
  const ushort* Bg = Bt + (size_t)(bn + 32 * wave + srow) * 256 + sch * 8;
  ushort* la[2] = { &As[0][(32 * wave) * 32], &As[1][(32 * wave) * 32] };
  ushort* lb[2] = { &Bs[0][(32 * wave) * 32], &Bs[1][(32 * wave) * 32] };

  f32x4 acc[4][4];
#pragma unroll
  for (int i = 0; i < 4; ++i)
#pragma unroll
    for (int j = 0; j < 4; ++j) acc[i][j] = (f32x4){0.f, 0.f, 0.f, 0.f};

  g2l(Ag, la[0]); g2l(Ag + 16 * 256, la[0] + 16 * 32);
  g2l(Bg, lb[0]); g2l(Bg + 16 * 256, lb[0] + 16 * 32);

  for (int k = 0; k < 8; ++k) {
    __syncthreads();
    const int cur = k & 1, nxt = cur ^ 1;
    if (k < 7) {
      int k1 = (k + 1) * 32;
      g2l(Ag + k1, la[nxt]); g2l(Ag + 16 * 256 + k1, la[nxt] + 16 * 32);
      g2l(Bg + k1, lb[nxt]); g2l(Bg + 16 * 256 + k1, lb[nxt] + 16 * 32);
    }
    bf16x8 af[4], bfr[4];
#pragma unroll
    for (int mi = 0; mi < 4; ++mi)
      af[mi] = *(const bf16x8*)&As[cur][(wm + mi * 16 + l15) * 32 + pc * 8];
#pragma unroll
    for (int ni = 0; ni < 4; ++ni)
      bfr[ni] = *(const bf16x8*)&Bs[cur][(wn + ni * 16 + l15) * 32 + pc * 8];
#pragma unroll
    for (int mi = 0; mi < 4; ++mi)
#pragma unroll
      for (int ni = 0; ni < 4; ++ni)
        acc[mi][ni] = __builtin_amdgcn_mfma_f32_16x16x32_bf16(af[mi], bfr[ni], acc[mi][ni], 0, 0, 0);
  }

#pragma unroll
  for (int mi = 0; mi < 4; ++mi)
#pragma unroll
    for (int ni = 0; ni < 4; ++ni) {
      int col = bn + wn + ni * 16 + l15;
      float bb = bias[col];
#pragma unroll
      for (int r = 0; r < 4; ++r) {
        int row = bm + wm + mi * 16 + l4 * 4 + r;
        C[(size_t)row * 256 + col] = acc[mi][ni][r] + bb;
      }
    }
}

// ---------------- deformable sampling ----------------
// v6 = owner-lane de-replication (r6, proven) + x-pair 8-lane groups (r2's
// segment-halving, now affordable) + 2-deep static pipeline (r7).
// 8 sub-lanes per (b,q,h): s = chq(0-3) | xside<<2. Each point needs TWO
// wave-loads (rows y0,y1), each 128B contiguous across the 8 lanes
// -> 8 address-segments per wave-instruction (was 16), 32 loads/thread
// (was 64), 256 fma/thread (was 512).
// Owner lane o=s&3 computes level-o geometry once incl. per-x-side lane
// weights pW0/pW1 (edge-exact: clamp+mask semantics of the reference);
// consumers select by xside after broadcast. shfl_xor(4) merges x-sides.
__device__ inline void fmah(float* a, uint4 u, float wv) {
  union { uint4 u; _Float16 h[8]; } c; c.u = u;
#pragma unroll
  for (int i = 0; i < 8; ++i) a[i] = fmaf((float)c.h[i], wv, a[i]);
}

__global__ __launch_bounds__(256) void msda_sample(
    const ushort* __restrict__ val, const float* __restrict__ offlog,
    const float* __restrict__ ref, ushort* __restrict__ interm) {
  int h   = blockIdx.x & 7;
  int z   = blockIdx.x >> 3;               // 0..1359
  int s   = threadIdx.x & 7;               // sub-lane in 8-lane group
  int o   = s & 3;                         // owned level
  bool xs = s >= 4;                        // x-side
  int bq  = z * 32 + (threadIdx.x >> 3);   // 1360*32 = 43520
  int b   = (bq >= QN) ? 1 : 0;
  const ushort* vbl = val + (size_t)((uint)(b * 8 + h) * (uint)QN) * 32u + (uint)(s * 8);

  // ---- softmax: lane handles level o's 4 logits (lanes 4-7 duplicate 0-3) ----
  const float* lgp = offlog + (size_t)bq * 384 + 256 + h * 16;
  float4 lg = *(const float4*)(lgp + o * 4);
  float m = fmaxf(fmaxf(lg.x, lg.y), fmaxf(lg.z, lg.w));
  m = fmaxf(m, __shfl_xor(m, 1, 64));
  m = fmaxf(m, __shfl_xor(m, 2, 64));
  float e0 = __expf(lg.x - m), e1 = __expf(lg.y - m),
        e2 = __expf(lg.z - m), e3 = __expf(lg.w - m);
  float ssum = e0 + e1 + e2 + e3;
  ssum += __shfl_xor(ssum, 1, 64);
  ssum += __shfl_xor(ssum, 2, 64);
  float inv = __builtin_amdgcn_rcpf(ssum);
  float aw[4] = { e0 * inv, e1 * inv, e2 * inv, e3 * inv };

  // ---- owned level geometry ----
  const int  Wl  = 128 >> o;                       // 128,64,32,16
  const uint t16 = 65536u >> (o + o);
  const int  lst = (int)((65536u - t16) / 3u);     // 0,16384,20480,21504
  const float fW = (float)Wl;
  const float* offp = offlog + (size_t)bq * 384 + h * 32;
  float4 f0 = *(const float4*)(offp + o * 8);
  float4 f1 = *(const float4*)(offp + o * 8 + 4);
  float2 rf = *(const float2*)(ref + (size_t)bq * 8 + o * 2);
  const float xb = rf.x * fW - 0.5f;
  const float yb = rf.y * fW - 0.5f;
  float ox[4] = { f0.x, f0.z, f1.x, f1.z };
  float oy[4] = { f0.y, f0.w, f1.y, f1.w };

  uint  pA0[4], pA1[4];
  float pW0[4], pW1[4], pY0[4], pY1[4];
#pragma unroll
  for (int p = 0; p < 4; ++p) {
    float x = xb + ox[p], y = yb + oy[p];
    float x0f = floorf(x), y0f = floorf(y);
    float fx = x - x0f, fy = y - y0f;
    int x0 = (int)x0f, y0 = (int)y0f;
    float a = aw[p];
    // masked corner weights (reference semantics)
    float wx0 = ((uint)x0       < (uint)Wl) ? (1.f - fx) : 0.f;
    float wx1 = ((uint)(x0 + 1) < (uint)Wl) ? fx         : 0.f;
    pY0[p] = (((uint)y0       < (uint)Wl) ? (1.f - fy) : 0.f) * a;
    pY1[p] = (((uint)(y0 + 1) < (uint)Wl) ? fy         : 0.f) * a;
    // clamped corner indices (reference semantics)
    int xc0 = min(max(x0, 0), Wl - 1);
    int xc1 = min(max(x0 + 1, 0), Wl - 1);
    int yc0 = min(max(y0, 0), Wl - 1);
    int yc1 = min(max(y0 + 1, 0), Wl - 1);
    // aligned x-pair base; lane xside reads pixel xbase+xside
    int xbase = min(max(x0, 0), Wl - 2);
    // per-x-side lane weights: sum of reference corner weights on that pixel
    pW0[p] = ((xbase     == xc0) ? wx0 : 0.f) + ((xbase     == xc1) ? wx1 : 0.f);
    pW1[p] = ((xbase + 1 == xc0) ? wx0 : 0.f) + ((xbase + 1 == xc1) ? wx1 : 0.f);
    pA0[p] = (uint)((lst + yc0 * Wl + xbase) * 32);   // elem offset, row y0
    pA1[p] = (uint)((lst + yc1 * Wl + xbase) * 32);   // elem offset, row y1
  }

  float acc[8];
#pragma unroll
  for (int i = 0; i < 8; ++i) acc[i] = 0.f;

  const int gb = (threadIdx.x & 63) & ~7;            // group base lane

  uint  bA0[2], bA1[2];
  float bW[2], bY0[2], bY1[2];
  uint4 u0[2], u1[2];

#define MSDA_BCAST(J, S) do {                                   \
    const int l_ = (J) >> 2, p_ = (J) & 3;                      \
    const int src_ = gb | l_;                                   \
    bA0[S] = (uint)__shfl((int)pA0[p_], src_, 64);              \
    bA1[S] = (uint)__shfl((int)pA1[p_], src_, 64);              \
    float w0_ = __shfl(pW0[p_], src_, 64);                      \
    float w1_ = __shfl(pW1[p_], src_, 64);                      \
    bW[S]  = xs ? w1_ : w0_;                                    \
    bY0[S] = __shfl(pY0[p_], src_, 64);                         \
    bY1[S] = __shfl(pY1[p_], src_, 64);                         \
  } while (0)
#define MSDA_LOAD(S) do {                                       \
    u0[S] = *(const uint4*)(vbl + bA0[S]);                      \
    u1[S] = *(const uint4*)(vbl + bA1[S]);                      \
  } while (0)

  MSDA_BCAST(0, 0);
  MSDA_LOAD(0);
#pragma unroll
  for (int j = 0; j < 16; ++j) {
    const int cur = j & 1, nxt = cur ^ 1;
    if (j < 15) { MSDA_BCAST(j + 1, nxt); MSDA_LOAD(nxt); }
    fmah(acc, u0[cur], bW[cur] * bY0[cur]);
    fmah(acc, u1[cur], bW[cur] * bY1[cur]);
  }
#undef MSDA_BCAST
#undef MSDA_LOAD

  // merge x-sides (lanes s and s^4 hold the two halves of the same chq)
#pragma unroll
  for (int i = 0; i < 8; ++i) acc[i] += __shfl_xor(acc[i], 4, 64);

  // each lane stores 8B: xside0 -> channels [chq*8, +4), xside1 -> +4..8
  uint2 ov;
  if (!xs) { ov.x = pk2(acc[0], acc[1]); ov.y = pk2(acc[2], acc[3]); }
  else     { ov.x = pk2(acc[4], acc[5]); ov.y = pk2(acc[6], acc[7]); }
  *(uint2*)(interm + (size_t)bq * 256 + h * 32 + (s & 3) * 8 + (xs ? 4 : 0)) = ov;
}

extern "C" void kernel_launch(void* const* d_in, const int* in_sizes, int n_in,
                              void* d_out, int out_size, void* d_ws, size_t ws_size,
                              hipStream_t stream) {
  const float* query = (const float*)d_in[0];
  const float* value = (const float*)d_in[1];
  const float* ref   = (const float*)d_in[2];
  const float* W_off  = (const float*)d_in[4];
  const float* b_off  = (const float*)d_in[5];
  const float* W_attn = (const float*)d_in[6];
  const float* b_attn = (const float*)d_in[7];
  const float* W_v    = (const float*)d_in[8];
  const float* b_v    = (const float*)d_in[9];
  const float* W_out  = (const float*)d_in[10];
  const float* b_out  = (const float*)d_in[11];
  float* out = (float*)d_out;

  // ---- workspace (byte offsets, 256-aligned) ----
  char* wsb = (char*)d_ws;
  ushort* ws_wv     = (ushort*)(wsb + 0);          // 131072 B
  ushort* ws_wol    = (ushort*)(wsb + 131072);     // 196608 B
  ushort* ws_wout   = (ushort*)(wsb + 327680);     // 131072 B
  float*  ws_biasf  = (float*)(wsb + 458752);      // 4096 B
  ushort* ws_val    = (ushort*)(wsb + 462848);     // 22282240 B fp16 head-split
  ushort* ws_interm = (ushort*)(wsb + 22745088);   // 22282240 B bf16 (M,256)
  float*  ws_offlog = (float*)(wsb + 45027328);    // 66846720 B f32 (M,384)
  size_t need = (size_t)45027328 + 66846720;       // ~112 MB
  if (ws_size < need) return;

  dim3 blk(256);
  prep_weights<<<dim3(896), blk, 0, stream>>>(W_v, W_out, W_off, W_attn, b_off, b_attn,
                                              ws_wv, ws_wout, ws_wol, ws_biasf);
  gemm_in<<<dim3(340, 5), blk, 0, stream>>>(value, query, ws_wv, ws_wol, b_v, ws_biasf,
                                            ws_val, ws_offlog);
  msda_sample<<<dim3(10880), blk, 0, stream>>>(ws_val, ws_offlog, ref, ws_interm);
  gemm_out<<<dim3(340, 2), blk, 0, stream>>>(ws_interm, ws_wout, b_out, out);
}

// Round 9
// 266.491 us; speedup vs baseline: 1.0485x; 1.0045x over previous
//
#include <hip/hip_runtime.h>
#include <math.h>

#define QN 21760
#define MTOT 43520      // = 340 * 128
#define SZBQC 11141120  // MTOT*256

typedef __attribute__((ext_vector_type(8))) short bf16x8;
typedef __attribute__((ext_vector_type(4))) float f32x4;

__device__ inline ushort f2bf(float f) {
  union { float f; uint u; } v; v.f = f;
  return (ushort)((v.u + 0x7FFFu + ((v.u >> 16) & 1u)) >> 16);
}
__device__ inline uint pk2(float lo, float hi) { return (uint)f2bf(lo) | ((uint)f2bf(hi) << 16); }

__device__ inline void g2l(const ushort* g, ushort* l) {
  __builtin_amdgcn_global_load_lds(
      (const __attribute__((address_space(1))) void*)g,
      (__attribute__((address_space(3))) void*)l, 16, 0, 0);
}

// ---------------- weight prep ----------------
__global__ __launch_bounds__(256) void prep_weights(
    const float* __restrict__ Wv, const float* __restrict__ Wout,
    const float* __restrict__ Woff, const float* __restrict__ Wattn,
    const float* __restrict__ boff, const float* __restrict__ battn,
    ushort* __restrict__ wv_t, ushort* __restrict__ wout_t,
    ushort* __restrict__ wol_t, float* __restrict__ biasf) {
  int bidx = blockIdx.x, t = threadIdx.x;
  if (bidx < 256) {
    int idx = bidx * 256 + t; int n = idx >> 8, k = idx & 255;
    wv_t[idx] = f2bf(Wv[(size_t)k * 256 + n]);
  } else if (bidx < 512) {
    int idx = (bidx - 256) * 256 + t; int n = idx >> 8, k = idx & 255;
    wout_t[idx] = f2bf(Wout[(size_t)k * 256 + n]);
  } else {
    int idx = (bidx - 512) * 256 + t; int n = idx >> 8, k = idx & 255;
    float v = (n < 256) ? Woff[(size_t)k * 256 + n] : Wattn[(size_t)k * 128 + (n - 256)];
    wol_t[idx] = f2bf(v);
    if (idx < 384) biasf[idx] = (idx < 256) ? boff[idx] : battn[idx - 256];
  }
}

// ---- XOR-swizzled LDS tile: 128 rows x 32 ushort; 16B chunk c of row r
// lives at physical chunk c ^ ((r>>1)&3). Frag reads are conflict-free. ----

// ---------------- fused input GEMM (val + offlog), cast-in-loop ----------------
__global__ __launch_bounds__(256) void gemm_in(
    const float* __restrict__ value, const float* __restrict__ query,
    const ushort* __restrict__ Wv, const ushort* __restrict__ Wol,
    const float* __restrict__ bv, const float* __restrict__ bol,
    ushort* __restrict__ val_out, float* __restrict__ offlog) {
  __shared__ ushort As[2][4096];
  __shared__ ushort Bs[2][4096];
  const int t = threadIdx.x, wave = t >> 6, lane = t & 63;
  const int bx = blockIdx.y, bm = blockIdx.x * 128;
  const bool isVal = bx < 2;
  const float* A   = isVal ? value : query;
  const ushort* Bt = isVal ? (Wv + (size_t)bx * 128 * 256)
                           : (Wol + (size_t)(bx - 2) * 128 * 256);
  const int wm = (wave >> 1) * 64, wn = (wave & 1) * 64;
  const int l15 = lane & 15, l4 = lane >> 4;
  const int pc = l4 ^ ((l15 >> 1) & 3);              // frag-read physical chunk

  const int srow = lane >> 2;
  const int sch  = (lane & 3) ^ ((lane >> 3) & 3);
  const ushort* Bg = Bt + (size_t)(32 * wave + srow) * 256 + sch * 8;
  ushort* lb[2] = { &Bs[0][(32 * wave) * 32], &Bs[1][(32 * wave) * 32] };

  f32x4 acc[4][4];
#pragma unroll
  for (int i = 0; i < 4; ++i)
#pragma unroll
    for (int j = 0; j < 4; ++j) acc[i][j] = (f32x4){0.f, 0.f, 0.f, 0.f};

  int arow[4], apart[4];
#pragma unroll
  for (int i = 0; i < 4; ++i) {
    int c = t + i * 256; arow[i] = c >> 3; apart[i] = c & 7;
  }

  {
    float4 pa[4];
#pragma unroll
    for (int i = 0; i < 4; ++i)
      pa[i] = *(const float4*)&A[(size_t)(bm + arow[i]) * 256 + apart[i] * 4];
    g2l(Bg, lb[0]); g2l(Bg + 16 * 256, lb[0] + 16 * 32);
#pragma unroll
    for (int i = 0; i < 4; ++i) {
      int pc16 = (apart[i] >> 1) ^ ((arow[i] >> 1) & 3);
      ushort4 hv = { f2bf(pa[i].x), f2bf(pa[i].y), f2bf(pa[i].z), f2bf(pa[i].w) };
      *(ushort4*)&As[0][arow[i] * 32 + pc16 * 8 + (apart[i] & 1) * 4] = hv;
    }
  }

  for (int k = 0; k < 8; ++k) {
    __syncthreads();
    const int cur = k & 1, nxt = cur ^ 1;
    float4 pa[4];
    if (k < 7) {
      int k1 = (k + 1) * 32;
#pragma unroll
      for (int i = 0; i < 4; ++i)
        pa[i] = *(const float4*)&A[(size_t)(bm + arow[i]) * 256 + k1 + apart[i] * 4];
      g2l(Bg + k1, lb[nxt]); g2l(Bg + 16 * 256 + k1, lb[nxt] + 16 * 32);
    }
    bf16x8 af[4], bfr[4];
#pragma unroll
    for (int mi = 0; mi < 4; ++mi)
      af[mi] = *(const bf16x8*)&As[cur][(wm + mi * 16 + l15) * 32 + pc * 8];
#pragma unroll
    for (int ni = 0; ni < 4; ++ni)
      bfr[ni] = *(const bf16x8*)&Bs[cur][(wn + ni * 16 + l15) * 32 + pc * 8];
#pragma unroll
    for (int mi = 0; mi < 4; ++mi)
#pragma unroll
      for (int ni = 0; ni < 4; ++ni)
        acc[mi][ni] = __builtin_amdgcn_mfma_f32_16x16x32_bf16(af[mi], bfr[ni], acc[mi][ni], 0, 0, 0);
    if (k < 7) {
#pragma unroll
      for (int i = 0; i < 4; ++i) {
        int pc16 = (apart[i] >> 1) ^ ((arow[i] >> 1) & 3);
        ushort4 hv = { f2bf(pa[i].x), f2bf(pa[i].y), f2bf(pa[i].z), f2bf(pa[i].w) };
        *(ushort4*)&As[nxt][arow[i] * 32 + pc16 * 8 + (apart[i] & 1) * 4] = hv;
      }
    }
  }

  if (isVal) {
    _Float16* vo = (_Float16*)val_out;
#pragma unroll
    for (int mi = 0; mi < 4; ++mi)
#pragma unroll
      for (int ni = 0; ni < 4; ++ni) {
        int col = bx * 128 + wn + ni * 16 + l15;
        float bb = bv[col];
        int hh = col >> 5, c = col & 31;
#pragma unroll
        for (int r = 0; r < 4; ++r) {
          int row = bm + wm + mi * 16 + l4 * 4 + r;
          int b = (row >= QN) ? 1 : 0;
          int vpos = row - b * QN;
          vo[((size_t)(b * 8 + hh) * QN + vpos) * 32 + c] = (_Float16)(acc[mi][ni][r] + bb);
        }
      }
  } else {
#pragma unroll
    for (int mi = 0; mi < 4; ++mi)
#pragma unroll
      for (int ni = 0; ni < 4; ++ni) {
        int col = (bx - 2) * 128 + wn + ni * 16 + l15;
        float bb = bol[col];
#pragma unroll
        for (int r = 0; r < 4; ++r) {
          int row = bm + wm + mi * 16 + l4 * 4 + r;
          offlog[(size_t)row * 384 + col] = acc[mi][ni][r] + bb;
        }
      }
  }
}

// ---------------- output GEMM (A bf16), dbuf, all-g2l, swizzled ----------------
__global__ __launch_bounds__(256) void gemm_out(
    const ushort* __restrict__ A, const ushort* __restrict__ Bt,
    const float* __restrict__ bias, float* __restrict__ C) {
  __shared__ ushort As[2][4096];
  __shared__ ushort Bs[2][4096];
  const int t = threadIdx.x, wave = t >> 6, lane = t & 63;
  const int bm = blockIdx.x * 128, bn = blockIdx.y * 128;
  const int wm = (wave >> 1) * 64, wn = (wave & 1) * 64;
  const int l15 = lane & 15, l4 = lane >> 4;
  const int pc = l4 ^ ((l15 >> 1) & 3);

  const int srow = lane >> 2;
  const int sch  = (lane & 3) ^ ((lane >> 3) & 3);
  const ushort* Ag = A + (size_t)(bm + 32 * wave + srow) * 256 + sch * 8;
  const ushort* Bg = Bt + (size_t)(bn + 32 * wave + srow) * 256 + sch * 8;
  ushort* la[2] = { &As[0][(32 * wave) * 32], &As[1][(32 * wave) * 32] };
  ushort* lb[2] = { &Bs[0][(32 * wave) * 32], &Bs[1][(32 * wave) * 32] };

  f32x4 acc[4][4];
#pragma unroll
  for (int i = 0; i < 4; ++i)
#pragma unroll
    for (int j = 0; j < 4; ++j) acc[i][j] = (f32x4){0.f, 0.f, 0.f, 0.f};

  g2l(Ag, la[0]); g2l(Ag + 16 * 256, la[0] + 16 * 32);
  g2l(Bg, lb[0]); g2l(Bg + 16 * 256, lb[0] + 16 * 32);

  for (int k = 0; k < 8; ++k) {
    __syncthreads();
    const int cur = k & 1, nxt = cur ^ 1;
    if (k < 7) {
      int k1 = (k + 1) * 32;
      g2l(Ag + k1, la[nxt]); g2l(Ag + 16 * 256 + k1, la[nxt] + 16 * 32);
      g2l(Bg + k1, lb[nxt]); g2l(Bg + 16 * 256 + k1, lb[nxt] + 16 * 32);
    }
    bf16x8 af[4], bfr[4];
#pragma unroll
    for (int mi = 0; mi < 4; ++mi)
      af[mi] = *(const bf16x8*)&As[cur][(wm + mi * 16 + l15) * 32 + pc * 8];
#pragma unroll
    for (int ni = 0; ni < 4; ++ni)
      bfr[ni] = *(const bf16x8*)&Bs[cur][(wn + ni * 16 + l15) * 32 + pc * 8];
#pragma unroll
    for (int mi = 0; mi < 4; ++mi)
#pragma unroll
      for (int ni = 0; ni < 4; ++ni)
        acc[mi][ni] = __builtin_amdgcn_mfma_f32_16x16x32_bf16(af[mi], bfr[ni], acc[mi][ni], 0, 0, 0);
  }

#pragma unroll
  for (int mi = 0; mi < 4; ++mi)
#pragma unroll
    for (int ni = 0; ni < 4; ++ni) {
      int col = bn + wn + ni * 16 + l15;
      float bb = bias[col];
#pragma unroll
      for (int r = 0; r < 4; ++r) {
        int row = bm + wm + mi * 16 + l4 * 4 + r;
        C[(size_t)row * 256 + col] = acc[mi][ni][r] + bb;
      }
    }
}

// ---------------- deformable sampling ----------------
// v7 = v6 (8-lane x-pair groups: 8 segments/wave-inst, 32 loads/thread)
// + POINT-PAIR ownership: lane s owns (level s&3, point-pair s>>2) —
// softmax exp over its 2 logits only (8-lane xor 1,2,4 reduce covers all
// 16 with ZERO duplication; v6 duplicated 2x) and geometry for 2 points
// only. Consumption role (x-side = s>>2, loads, fma) unchanged from v6.
__device__ inline void fmah(float* a, uint4 u, float wv) {
  union { uint4 u; _Float16 h[8]; } c; c.u = u;
#pragma unroll
  for (int i = 0; i < 8; ++i) a[i] = fmaf((float)c.h[i], wv, a[i]);
}

__global__ __launch_bounds__(256) void msda_sample(
    const ushort* __restrict__ val, const float* __restrict__ offlog,
    const float* __restrict__ ref, ushort* __restrict__ interm) {
  int h   = blockIdx.x & 7;
  int z   = blockIdx.x >> 3;               // 0..1359
  int s   = threadIdx.x & 7;               // sub-lane in 8-lane group
  int o   = s & 3;                         // owned level
  int pp  = s >> 2;                        // owned point-pair (pts 2pp, 2pp+1)
  bool xs = s >= 4;                        // consumed x-side
  int bq  = z * 32 + (threadIdx.x >> 3);   // 1360*32 = 43520
  int b   = (bq >= QN) ? 1 : 0;
  const ushort* vbl = val + (size_t)((uint)(b * 8 + h) * (uint)QN) * 32u + (uint)(s * 8);

  // ---- softmax: lane owns 2 logits (level o, points 2pp,2pp+1) ----
  const float* lgp = offlog + (size_t)bq * 384 + 256 + h * 16;
  float2 lg = *(const float2*)(lgp + o * 4 + pp * 2);
  float m = fmaxf(lg.x, lg.y);
  m = fmaxf(m, __shfl_xor(m, 1, 64));
  m = fmaxf(m, __shfl_xor(m, 2, 64));
  m = fmaxf(m, __shfl_xor(m, 4, 64));
  float e0 = __expf(lg.x - m), e1 = __expf(lg.y - m);
  float ssum = e0 + e1;
  ssum += __shfl_xor(ssum, 1, 64);
  ssum += __shfl_xor(ssum, 2, 64);
  ssum += __shfl_xor(ssum, 4, 64);
  float inv = __builtin_amdgcn_rcpf(ssum);
  float aw0 = e0 * inv, aw1 = e1 * inv;

  // ---- owned geometry: level o, points 2pp and 2pp+1 ----
  const int  Wl  = 128 >> o;                       // 128,64,32,16
  const uint t16 = 65536u >> (o + o);
  const int  lst = (int)((65536u - t16) / 3u);     // 0,16384,20480,21504
  const float fW = (float)Wl;
  const float* offp = offlog + (size_t)bq * 384 + h * 32;
  float4 f0 = *(const float4*)(offp + o * 8 + pp * 4);   // ox,oy for 2 pts
  float2 rf = *(const float2*)(ref + (size_t)bq * 8 + o * 2);
  const float xb = rf.x * fW - 0.5f;
  const float yb = rf.y * fW - 0.5f;
  float ox[2] = { f0.x, f0.z };
  float oy[2] = { f0.y, f0.w };
  float awq[2] = { aw0, aw1 };

  uint  pA0[2], pA1[2];
  float pW0[2], pW1[2], pY0[2], pY1[2];
#pragma unroll
  for (int q = 0; q < 2; ++q) {
    float x = xb + ox[q], y = yb + oy[q];
    float x0f = floorf(x), y0f = floorf(y);
    float fx = x - x0f, fy = y - y0f;
    int x0 = (int)x0f, y0 = (int)y0f;
    float a = awq[q];
    // masked corner weights (reference semantics)
    float wx0 = ((uint)x0       < (uint)Wl) ? (1.f - fx) : 0.f;
    float wx1 = ((uint)(x0 + 1) < (uint)Wl) ? fx         : 0.f;
    pY0[q] = (((uint)y0       < (uint)Wl) ? (1.f - fy) : 0.f) * a;
    pY1[q] = (((uint)(y0 + 1) < (uint)Wl) ? fy         : 0.f) * a;
    // clamped corner indices (reference semantics)
    int xc0 = min(max(x0, 0), Wl - 1);
    int xc1 = min(max(x0 + 1, 0), Wl - 1);
    int yc0 = min(max(y0, 0), Wl - 1);
    int yc1 = min(max(y0 + 1, 0), Wl - 1);
    // aligned x-pair base; consumer lane xside reads pixel xbase+xside
    int xbase = min(max(x0, 0), Wl - 2);
    // per-x-side lane weights: sum of reference corner weights on that pixel
    pW0[q] = ((xbase     == xc0) ? wx0 : 0.f) + ((xbase     == xc1) ? wx1 : 0.f);
    pW1[q] = ((xbase + 1 == xc0) ? wx0 : 0.f) + ((xbase + 1 == xc1) ? wx1 : 0.f);
    pA0[q] = (uint)((lst + yc0 * Wl + xbase) * 32);   // elem offset, row y0
    pA1[q] = (uint)((lst + yc1 * Wl + xbase) * 32);   // elem offset, row y1
  }

  float acc[8];
#pragma unroll
  for (int i = 0; i < 8; ++i) acc[i] = 0.f;

  const int gb = (threadIdx.x & 63) & ~7;            // group base lane

  uint  bA0[2], bA1[2];
  float bW[2], bY0[2], bY1[2];
  uint4 u0[2], u1[2];

  // point j: level l=j>>2, point p=j&3 -> owner lane gb|((p>>1)<<2)|l,
  // owner array slot p&1 (all compile-time under full unroll).
#define MSDA_BCAST(J, S) do {                                   \
    const int l_ = (J) >> 2, p_ = (J) & 3;                      \
    const int src_ = gb | ((p_ >> 1) << 2) | l_;                \
    const int q_ = p_ & 1;                                      \
    bA0[S] = (uint)__shfl((int)pA0[q_], src_, 64);              \
    bA1[S] = (uint)__shfl((int)pA1[q_], src_, 64);              \
    float w0_ = __shfl(pW0[q_], src_, 64);                      \
    float w1_ = __shfl(pW1[q_], src_, 64);                      \
    bW[S]  = xs ? w1_ : w0_;                                    \
    bY0[S] = __shfl(pY0[q_], src_, 64);                         \
    bY1[S] = __shfl(pY1[q_], src_, 64);                         \
  } while (0)
#define MSDA_LOAD(S) do {                                       \
    u0[S] = *(const uint4*)(vbl + bA0[S]);                      \
    u1[S] = *(const uint4*)(vbl + bA1[S]);                      \
  } while (0)

  MSDA_BCAST(0, 0);
  MSDA_LOAD(0);
#pragma unroll
  for (int j = 0; j < 16; ++j) {
    const int cur = j & 1, nxt = cur ^ 1;
    if (j < 15) { MSDA_BCAST(j + 1, nxt); MSDA_LOAD(nxt); }
    fmah(acc, u0[cur], bW[cur] * bY0[cur]);
    fmah(acc, u1[cur], bW[cur] * bY1[cur]);
  }
#undef MSDA_BCAST
#undef MSDA_LOAD

  // merge x-sides (lanes s and s^4 hold the two halves of the same chq)
#pragma unroll
  for (int i = 0; i < 8; ++i) acc[i] += __shfl_xor(acc[i], 4, 64);

  // each lane stores 8B: xside0 -> channels [chq*8, +4), xside1 -> +4..8
  uint2 ov;
  if (!xs) { ov.x = pk2(acc[0], acc[1]); ov.y = pk2(acc[2], acc[3]); }
  else     { ov.x = pk2(acc[4], acc[5]); ov.y = pk2(acc[6], acc[7]); }
  *(uint2*)(interm + (size_t)bq * 256 + h * 32 + (s & 3) * 8 + (xs ? 4 : 0)) = ov;
}

extern "C" void kernel_launch(void* const* d_in, const int* in_sizes, int n_in,
                              void* d_out, int out_size, void* d_ws, size_t ws_size,
                              hipStream_t stream) {
  const float* query = (const float*)d_in[0];
  const float* value = (const float*)d_in[1];
  const float* ref   = (const float*)d_in[2];
  const float* W_off  = (const float*)d_in[4];
  const float* b_off  = (const float*)d_in[5];
  const float* W_attn = (const float*)d_in[6];
  const float* b_attn = (const float*)d_in[7];
  const float* W_v    = (const float*)d_in[8];
  const float* b_v    = (const float*)d_in[9];
  const float* W_out  = (const float*)d_in[10];
  const float* b_out  = (const float*)d_in[11];
  float* out = (float*)d_out;

  // ---- workspace (byte offsets, 256-aligned) ----
  char* wsb = (char*)d_ws;
  ushort* ws_wv     = (ushort*)(wsb + 0);          // 131072 B
  ushort* ws_wol    = (ushort*)(wsb + 131072);     // 196608 B
  ushort* ws_wout   = (ushort*)(wsb + 327680);     // 131072 B
  float*  ws_biasf  = (float*)(wsb + 458752);      // 4096 B
  ushort* ws_val    = (ushort*)(wsb + 462848);     // 22282240 B fp16 head-split
  ushort* ws_interm = (ushort*)(wsb + 22745088);   // 22282240 B bf16 (M,256)
  float*  ws_offlog = (float*)(wsb + 45027328);    // 66846720 B f32 (M,384)
  size_t need = (size_t)45027328 + 66846720;       // ~112 MB
  if (ws_size < need) return;

  dim3 blk(256);
  prep_weights<<<dim3(896), blk, 0, stream>>>(W_v, W_out, W_off, W_attn, b_off, b_attn,
                                              ws_wv, ws_wout, ws_wol, ws_biasf);
  gemm_in<<<dim3(340, 5), blk, 0, stream>>>(value, query, ws_wv, ws_wol, b_v, ws_biasf,
                                            ws_val, ws_offlog);
  msda_sample<<<dim3(10880), blk, 0, stream>>>(ws_val, ws_offlog, ref, ws_interm);
  gemm_out<<<dim3(340, 2), blk, 0, stream>>>(ws_interm, ws_wout, b_out, out);
}

// Round 10
// 262.217 us; speedup vs baseline: 1.0656x; 1.0163x over previous
//
#include <hip/hip_runtime.h>
#include <hip/hip_cooperative_groups.h>
#include <math.h>

namespace cg = cooperative_groups;

#define QN 21760
#define MTOT 43520      // = 340 * 128
#define SZBQC 11141120  // MTOT*256

typedef __attribute__((ext_vector_type(8))) short bf16x8;
typedef __attribute__((ext_vector_type(4))) float f32x4;

__device__ inline ushort f2bf(float f) {
  union { float f; uint u; } v; v.f = f;
  return (ushort)((v.u + 0x7FFFu + ((v.u >> 16) & 1u)) >> 16);
}
__device__ inline uint pk2(float lo, float hi) { return (uint)f2bf(lo) | ((uint)f2bf(hi) << 16); }

__device__ inline void g2l(const ushort* g, ushort* l) {
  __builtin_amdgcn_global_load_lds(
      (const __attribute__((address_space(1))) void*)g,
      (__attribute__((address_space(3))) void*)l, 16, 0, 0);
}

// ================= phase bodies (bit-identical to r9 kernels) =================

__device__ __forceinline__ void prep_body(
    int bidx, int t,
    const float* __restrict__ Wv, const float* __restrict__ Wout,
    const float* __restrict__ Woff, const float* __restrict__ Wattn,
    const float* __restrict__ boff, const float* __restrict__ battn,
    ushort* __restrict__ wv_t, ushort* __restrict__ wout_t,
    ushort* __restrict__ wol_t, float* __restrict__ biasf) {
  if (bidx < 256) {
    int idx = bidx * 256 + t; int n = idx >> 8, k = idx & 255;
    wv_t[idx] = f2bf(Wv[(size_t)k * 256 + n]);
  } else if (bidx < 512) {
    int idx = (bidx - 256) * 256 + t; int n = idx >> 8, k = idx & 255;
    wout_t[idx] = f2bf(Wout[(size_t)k * 256 + n]);
  } else {
    int idx = (bidx - 512) * 256 + t; int n = idx >> 8, k = idx & 255;
    float v = (n < 256) ? Woff[(size_t)k * 256 + n] : Wattn[(size_t)k * 128 + (n - 256)];
    wol_t[idx] = f2bf(v);
    if (idx < 384) biasf[idx] = (idx < 256) ? boff[idx] : battn[idx - 256];
  }
}

// ---- XOR-swizzled LDS tile: 128 rows x 32 ushort; 16B chunk c of row r
// lives at physical chunk c ^ ((r>>1)&3). Frag reads are conflict-free. ----

__device__ __forceinline__ void gemm_in_body(
    ushort (*As)[4096], ushort (*Bs)[4096], int bxv, int bx, int t,
    const float* __restrict__ value, const float* __restrict__ query,
    const ushort* __restrict__ Wv, const ushort* __restrict__ Wol,
    const float* __restrict__ bv, const float* __restrict__ bol,
    ushort* __restrict__ val_out, float* __restrict__ offlog) {
  const int wave = t >> 6, lane = t & 63;
  const int bm = bxv * 128;
  const bool isVal = bx < 2;
  const float* A   = isVal ? value : query;
  const ushort* Bt = isVal ? (Wv + (size_t)bx * 128 * 256)
                           : (Wol + (size_t)(bx - 2) * 128 * 256);
  const int wm = (wave >> 1) * 64, wn = (wave & 1) * 64;
  const int l15 = lane & 15, l4 = lane >> 4;
  const int pc = l4 ^ ((l15 >> 1) & 3);              // frag-read physical chunk

  const int srow = lane >> 2;
  const int sch  = (lane & 3) ^ ((lane >> 3) & 3);
  const ushort* Bg = Bt + (size_t)(32 * wave + srow) * 256 + sch * 8;
  ushort* lb[2] = { &Bs[0][(32 * wave) * 32], &Bs[1][(32 * wave) * 32] };

  f32x4 acc[4][4];
#pragma unroll
  for (int i = 0; i < 4; ++i)
#pragma unroll
    for (int j = 0; j < 4; ++j) acc[i][j] = (f32x4){0.f, 0.f, 0.f, 0.f};

  int arow[4], apart[4];
#pragma unroll
  for (int i = 0; i < 4; ++i) {
    int c = t + i * 256; arow[i] = c >> 3; apart[i] = c & 7;
  }

  {
    float4 pa[4];
#pragma unroll
    for (int i = 0; i < 4; ++i)
      pa[i] = *(const float4*)&A[(size_t)(bm + arow[i]) * 256 + apart[i] * 4];
    g2l(Bg, lb[0]); g2l(Bg + 16 * 256, lb[0] + 16 * 32);
#pragma unroll
    for (int i = 0; i < 4; ++i) {
      int pc16 = (apart[i] >> 1) ^ ((arow[i] >> 1) & 3);
      ushort4 hv = { f2bf(pa[i].x), f2bf(pa[i].y), f2bf(pa[i].z), f2bf(pa[i].w) };
      *(ushort4*)&As[0][arow[i] * 32 + pc16 * 8 + (apart[i] & 1) * 4] = hv;
    }
  }

  for (int k = 0; k < 8; ++k) {
    __syncthreads();
    const int cur = k & 1, nxt = cur ^ 1;
    float4 pa[4];
    if (k < 7) {
      int k1 = (k + 1) * 32;
#pragma unroll
      for (int i = 0; i < 4; ++i)
        pa[i] = *(const float4*)&A[(size_t)(bm + arow[i]) * 256 + k1 + apart[i] * 4];
      g2l(Bg + k1, lb[nxt]); g2l(Bg + 16 * 256 + k1, lb[nxt] + 16 * 32);
    }
    bf16x8 af[4], bfr[4];
#pragma unroll
    for (int mi = 0; mi < 4; ++mi)
      af[mi] = *(const bf16x8*)&As[cur][(wm + mi * 16 + l15) * 32 + pc * 8];
#pragma unroll
    for (int ni = 0; ni < 4; ++ni)
      bfr[ni] = *(const bf16x8*)&Bs[cur][(wn + ni * 16 + l15) * 32 + pc * 8];
#pragma unroll
    for (int mi = 0; mi < 4; ++mi)
#pragma unroll
      for (int ni = 0; ni < 4; ++ni)
        acc[mi][ni] = __builtin_amdgcn_mfma_f32_16x16x32_bf16(af[mi], bfr[ni], acc[mi][ni], 0, 0, 0);
    if (k < 7) {
#pragma unroll
      for (int i = 0; i < 4; ++i) {
        int pc16 = (apart[i] >> 1) ^ ((arow[i] >> 1) & 3);
        ushort4 hv = { f2bf(pa[i].x), f2bf(pa[i].y), f2bf(pa[i].z), f2bf(pa[i].w) };
        *(ushort4*)&As[nxt][arow[i] * 32 + pc16 * 8 + (apart[i] & 1) * 4] = hv;
      }
    }
  }

  if (isVal) {
    _Float16* vo = (_Float16*)val_out;
#pragma unroll
    for (int mi = 0; mi < 4; ++mi)
#pragma unroll
      for (int ni = 0; ni < 4; ++ni) {
        int col = bx * 128 + wn + ni * 16 + l15;
        float bb = bv[col];
        int hh = col >> 5, c = col & 31;
#pragma unroll
        for (int r = 0; r < 4; ++r) {
          int row = bm + wm + mi * 16 + l4 * 4 + r;
          int b = (row >= QN) ? 1 : 0;
          int vpos = row - b * QN;
          vo[((size_t)(b * 8 + hh) * QN + vpos) * 32 + c] = (_Float16)(acc[mi][ni][r] + bb);
        }
      }
  } else {
#pragma unroll
    for (int mi = 0; mi < 4; ++mi)
#pragma unroll
      for (int ni = 0; ni < 4; ++ni) {
        int col = (bx - 2) * 128 + wn + ni * 16 + l15;
        float bb = bol[col];
#pragma unroll
        for (int r = 0; r < 4; ++r) {
          int row = bm + wm + mi * 16 + l4 * 4 + r;
          offlog[(size_t)row * 384 + col] = acc[mi][ni][r] + bb;
        }
      }
  }
}

__device__ __forceinline__ void gemm_out_body(
    ushort (*As)[4096], ushort (*Bs)[4096], int bxv, int byv, int t,
    const ushort* __restrict__ A, const ushort* __restrict__ Bt,
    const float* __restrict__ bias, float* __restrict__ C) {
  const int wave = t >> 6, lane = t & 63;
  const int bm = bxv * 128, bn = byv * 128;
  const int wm = (wave >> 1) * 64, wn = (wave & 1) * 64;
  const int l15 = lane & 15, l4 = lane >> 4;
  const int pc = l4 ^ ((l15 >> 1) & 3);

  const int srow = lane >> 2;
  const int sch  = (lane & 3) ^ ((lane >> 3) & 3);
  const ushort* Ag = A + (size_t)(bm + 32 * wave + srow) * 256 + sch * 8;
  const ushort* Bg = Bt + (size_t)(bn + 32 * wave + srow) * 256 + sch * 8;
  ushort* la[2] = { &As[0][(32 * wave) * 32], &As[1][(32 * wave) * 32] };
  ushort* lb[2] = { &Bs[0][(32 * wave) * 32], &Bs[1][(32 * wave) * 32] };

  f32x4 acc[4][4];
#pragma unroll
  for (int i = 0; i < 4; ++i)
#pragma unroll
    for (int j = 0; j < 4; ++j) acc[i][j] = (f32x4){0.f, 0.f, 0.f, 0.f};

  g2l(Ag, la[0]); g2l(Ag + 16 * 256, la[0] + 16 * 32);
  g2l(Bg, lb[0]); g2l(Bg + 16 * 256, lb[0] + 16 * 32);

  for (int k = 0; k < 8; ++k) {
    __syncthreads();
    const int cur = k & 1, nxt = cur ^ 1;
    if (k < 7) {
      int k1 = (k + 1) * 32;
      g2l(Ag + k1, la[nxt]); g2l(Ag + 16 * 256 + k1, la[nxt] + 16 * 32);
      g2l(Bg + k1, lb[nxt]); g2l(Bg + 16 * 256 + k1, lb[nxt] + 16 * 32);
    }
    bf16x8 af[4], bfr[4];
#pragma unroll
    for (int mi = 0; mi < 4; ++mi)
      af[mi] = *(const bf16x8*)&As[cur][(wm + mi * 16 + l15) * 32 + pc * 8];
#pragma unroll
    for (int ni = 0; ni < 4; ++ni)
      bfr[ni] = *(const bf16x8*)&Bs[cur][(wn + ni * 16 + l15) * 32 + pc * 8];
#pragma unroll
    for (int mi = 0; mi < 4; ++mi)
#pragma unroll
      for (int ni = 0; ni < 4; ++ni)
        acc[mi][ni] = __builtin_amdgcn_mfma_f32_16x16x32_bf16(af[mi], bfr[ni], acc[mi][ni], 0, 0, 0);
  }

#pragma unroll
  for (int mi = 0; mi < 4; ++mi)
#pragma unroll
    for (int ni = 0; ni < 4; ++ni) {
      int col = bn + wn + ni * 16 + l15;
      float bb = bias[col];
#pragma unroll
      for (int r = 0; r < 4; ++r) {
        int row = bm + wm + mi * 16 + l4 * 4 + r;
        C[(size_t)row * 256 + col] = acc[mi][ni][r] + bb;
      }
    }
}

// msda v7 body (8-lane x-pair groups + point-pair ownership) — unchanged
__device__ __forceinline__ void fmah(float* a, uint4 u, float wv) {
  union { uint4 u; _Float16 h[8]; } c; c.u = u;
#pragma unroll
  for (int i = 0; i < 8; ++i) a[i] = fmaf((float)c.h[i], wv, a[i]);
}

__device__ __forceinline__ void msda_body(
    int vb, int tix,
    const ushort* __restrict__ val, const float* __restrict__ offlog,
    const float* __restrict__ ref, ushort* __restrict__ interm) {
  int h   = vb & 7;
  int z   = vb >> 3;                 // 0..1359
  int s   = tix & 7;                 // sub-lane in 8-lane group
  int o   = s & 3;                   // owned level
  int pp  = s >> 2;                  // owned point-pair (pts 2pp, 2pp+1)
  bool xs = s >= 4;                  // consumed x-side
  int bq  = z * 32 + (tix >> 3);     // 1360*32 = 43520
  int b   = (bq >= QN) ? 1 : 0;
  const ushort* vbl = val + (size_t)((uint)(b * 8 + h) * (uint)QN) * 32u + (uint)(s * 8);

  const float* lgp = offlog + (size_t)bq * 384 + 256 + h * 16;
  float2 lg = *(const float2*)(lgp + o * 4 + pp * 2);
  float m = fmaxf(lg.x, lg.y);
  m = fmaxf(m, __shfl_xor(m, 1, 64));
  m = fmaxf(m, __shfl_xor(m, 2, 64));
  m = fmaxf(m, __shfl_xor(m, 4, 64));
  float e0 = __expf(lg.x - m), e1 = __expf(lg.y - m);
  float ssum = e0 + e1;
  ssum += __shfl_xor(ssum, 1, 64);
  ssum += __shfl_xor(ssum, 2, 64);
  ssum += __shfl_xor(ssum, 4, 64);
  float inv = __builtin_amdgcn_rcpf(ssum);
  float aw0 = e0 * inv, aw1 = e1 * inv;

  const int  Wl  = 128 >> o;                       // 128,64,32,16
  const uint t16 = 65536u >> (o + o);
  const int  lst = (int)((65536u - t16) / 3u);     // 0,16384,20480,21504
  const float fW = (float)Wl;
  const float* offp = offlog + (size_t)bq * 384 + h * 32;
  float4 f0 = *(const float4*)(offp + o * 8 + pp * 4);   // ox,oy for 2 pts
  float2 rf = *(const float2*)(ref + (size_t)bq * 8 + o * 2);
  const float xb = rf.x * fW - 0.5f;
  const float yb = rf.y * fW - 0.5f;
  float ox[2] = { f0.x, f0.z };
  float oy[2] = { f0.y, f0.w };
  float awq[2] = { aw0, aw1 };

  uint  pA0[2], pA1[2];
  float pW0[2], pW1[2], pY0[2], pY1[2];
#pragma unroll
  for (int q = 0; q < 2; ++q) {
    float x = xb + ox[q], y = yb + oy[q];
    float x0f = floorf(x), y0f = floorf(y);
    float fx = x - x0f, fy = y - y0f;
    int x0 = (int)x0f, y0 = (int)y0f;
    float a = awq[q];
    float wx0 = ((uint)x0       < (uint)Wl) ? (1.f - fx) : 0.f;
    float wx1 = ((uint)(x0 + 1) < (uint)Wl) ? fx         : 0.f;
    pY0[q] = (((uint)y0       < (uint)Wl) ? (1.f - fy) : 0.f) * a;
    pY1[q] = (((uint)(y0 + 1) < (uint)Wl) ? fy         : 0.f) * a;
    int xc0 = min(max(x0, 0), Wl - 1);
    int xc1 = min(max(x0 + 1, 0), Wl - 1);
    int yc0 = min(max(y0, 0), Wl - 1);
    int yc1 = min(max(y0 + 1, 0), Wl - 1);
    int xbase = min(max(x0, 0), Wl - 2);
    pW0[q] = ((xbase     == xc0) ? wx0 : 0.f) + ((xbase     == xc1) ? wx1 : 0.f);
    pW1[q] = ((xbase + 1 == xc0) ? wx0 : 0.f) + ((xbase + 1 == xc1) ? wx1 : 0.f);
    pA0[q] = (uint)((lst + yc0 * Wl + xbase) * 32);
    pA1[q] = (uint)((lst + yc1 * Wl + xbase) * 32);
  }

  float acc[8];
#pragma unroll
  for (int i = 0; i < 8; ++i) acc[i] = 0.f;

  const int gb = (tix & 63) & ~7;                  // group base lane

  uint  bA0[2], bA1[2];
  float bW[2], bY0[2], bY1[2];
  uint4 u0[2], u1[2];

#define MSDA_BCAST(J, S) do {                                   \
    const int l_ = (J) >> 2, p_ = (J) & 3;                      \
    const int src_ = gb | ((p_ >> 1) << 2) | l_;                \
    const int q_ = p_ & 1;                                      \
    bA0[S] = (uint)__shfl((int)pA0[q_], src_, 64);              \
    bA1[S] = (uint)__shfl((int)pA1[q_], src_, 64);              \
    float w0_ = __shfl(pW0[q_], src_, 64);                      \
    float w1_ = __shfl(pW1[q_], src_, 64);                      \
    bW[S]  = xs ? w1_ : w0_;                                    \
    bY0[S] = __shfl(pY0[q_], src_, 64);                         \
    bY1[S] = __shfl(pY1[q_], src_, 64);                         \
  } while (0)
#define MSDA_LOAD(S) do {                                       \
    u0[S] = *(const uint4*)(vbl + bA0[S]);                      \
    u1[S] = *(const uint4*)(vbl + bA1[S]);                      \
  } while (0)

  MSDA_BCAST(0, 0);
  MSDA_LOAD(0);
#pragma unroll
  for (int j = 0; j < 16; ++j) {
    const int cur = j & 1, nxt = cur ^ 1;
    if (j < 15) { MSDA_BCAST(j + 1, nxt); MSDA_LOAD(nxt); }
    fmah(acc, u0[cur], bW[cur] * bY0[cur]);
    fmah(acc, u1[cur], bW[cur] * bY1[cur]);
  }
#undef MSDA_BCAST
#undef MSDA_LOAD

#pragma unroll
  for (int i = 0; i < 8; ++i) acc[i] += __shfl_xor(acc[i], 4, 64);

  uint2 ov;
  if (!xs) { ov.x = pk2(acc[0], acc[1]); ov.y = pk2(acc[2], acc[3]); }
  else     { ov.x = pk2(acc[4], acc[5]); ov.y = pk2(acc[6], acc[7]); }
  *(uint2*)(interm + (size_t)bq * 256 + h * 32 + (s & 3) * 8 + (xs ? 4 : 0)) = ov;
}

// ================= standalone wrappers (fallback path) =================

__global__ __launch_bounds__(256) void prep_weights(
    const float* Wv, const float* Wout, const float* Woff, const float* Wattn,
    const float* boff, const float* battn,
    ushort* wv_t, ushort* wout_t, ushort* wol_t, float* biasf) {
  prep_body(blockIdx.x, threadIdx.x, Wv, Wout, Woff, Wattn, boff, battn,
            wv_t, wout_t, wol_t, biasf);
}

__global__ __launch_bounds__(256) void gemm_in(
    const float* value, const float* query, const ushort* Wv, const ushort* Wol,
    const float* bv, const float* bol, ushort* val_out, float* offlog) {
  __shared__ ushort As[2][4096];
  __shared__ ushort Bs[2][4096];
  gemm_in_body(As, Bs, blockIdx.x, blockIdx.y, threadIdx.x,
               value, query, Wv, Wol, bv, bol, val_out, offlog);
}

__global__ __launch_bounds__(256) void gemm_out(
    const ushort* A, const ushort* Bt, const float* bias, float* C) {
  __shared__ ushort As[2][4096];
  __shared__ ushort Bs[2][4096];
  gemm_out_body(As, Bs, blockIdx.x, blockIdx.y, threadIdx.x, A, Bt, bias, C);
}

__global__ __launch_bounds__(256) void msda_sample(
    const ushort* val, const float* offlog, const float* ref, ushort* interm) {
  msda_body(blockIdx.x, threadIdx.x, val, offlog, ref, interm);
}

// ================= fused cooperative kernel =================

struct FusedArgs {
  const float *query, *value, *ref;
  const float *Woff, *boff, *Wattn, *battn, *Wv, *bv, *Wout, *bout;
  ushort *ws_wv, *ws_wol, *ws_wout;
  float *ws_biasf;
  ushort *ws_val, *ws_interm;
  float *ws_offlog;
  float *out;
};

__global__ __launch_bounds__(256) void fused_all(FusedArgs a) {
  __shared__ ushort As[2][4096];
  __shared__ ushort Bs[2][4096];
  cg::grid_group grid = cg::this_grid();
  const int t = threadIdx.x;
  const int g0 = blockIdx.x, gs = gridDim.x;

  // phase 1: weight prep
  for (int vb = g0; vb < 896; vb += gs)
    prep_body(vb, t, a.Wv, a.Wout, a.Woff, a.Wattn, a.boff, a.battn,
              a.ws_wv, a.ws_wout, a.ws_wol, a.ws_biasf);
  __builtin_amdgcn_fence(__ATOMIC_RELEASE, "agent");
  grid.sync();
  __builtin_amdgcn_fence(__ATOMIC_ACQUIRE, "agent");

  // phase 2: input GEMM (1700 virtual tiles)
  for (int vb = g0; vb < 1700; vb += gs) {
    gemm_in_body(As, Bs, vb % 340, vb / 340, t,
                 a.value, a.query, a.ws_wv, a.ws_wol, a.bv, a.ws_biasf,
                 a.ws_val, a.ws_offlog);
    __syncthreads();
  }
  __builtin_amdgcn_fence(__ATOMIC_RELEASE, "agent");
  grid.sync();
  __builtin_amdgcn_fence(__ATOMIC_ACQUIRE, "agent");

  // phase 3: deformable sampling (10880 virtual blocks)
  for (int vb = g0; vb < 10880; vb += gs)
    msda_body(vb, t, a.ws_val, a.ws_offlog, a.ref, a.ws_interm);
  __builtin_amdgcn_fence(__ATOMIC_RELEASE, "agent");
  grid.sync();
  __builtin_amdgcn_fence(__ATOMIC_ACQUIRE, "agent");

  // phase 4: output GEMM (680 virtual tiles)
  for (int vb = g0; vb < 680; vb += gs) {
    gemm_out_body(As, Bs, vb % 340, vb / 340, t,
                  a.ws_interm, a.ws_wout, a.bout, a.out);
    __syncthreads();
  }
}

// ================= host =================

extern "C" void kernel_launch(void* const* d_in, const int* in_sizes, int n_in,
                              void* d_out, int out_size, void* d_ws, size_t ws_size,
                              hipStream_t stream) {
  const float* query = (const float*)d_in[0];
  const float* value = (const float*)d_in[1];
  const float* ref   = (const float*)d_in[2];
  const float* W_off  = (const float*)d_in[4];
  const float* b_off  = (const float*)d_in[5];
  const float* W_attn = (const float*)d_in[6];
  const float* b_attn = (const float*)d_in[7];
  const float* W_v    = (const float*)d_in[8];
  const float* b_v    = (const float*)d_in[9];
  const float* W_out  = (const float*)d_in[10];
  const float* b_out  = (const float*)d_in[11];
  float* out = (float*)d_out;

  // ---- workspace (byte offsets, 256-aligned) ----
  char* wsb = (char*)d_ws;
  ushort* ws_wv     = (ushort*)(wsb + 0);          // 131072 B
  ushort* ws_wol    = (ushort*)(wsb + 131072);     // 196608 B
  ushort* ws_wout   = (ushort*)(wsb + 327680);     // 131072 B
  float*  ws_biasf  = (float*)(wsb + 458752);      // 4096 B
  ushort* ws_val    = (ushort*)(wsb + 462848);     // 22282240 B fp16 head-split
  ushort* ws_interm = (ushort*)(wsb + 22745088);   // 22282240 B bf16 (M,256)
  float*  ws_offlog = (float*)(wsb + 45027328);    // 66846720 B f32 (M,384)
  size_t need = (size_t)45027328 + 66846720;       // ~112 MB
  if (ws_size < need) return;

  dim3 blk(256);

  // ---- preferred path: single cooperative launch (kills inter-dispatch gaps) ----
  bool coop_done = false;
  int nb = 0;
  if (hipOccupancyMaxActiveBlocksPerMultiprocessor(&nb, (const void*)fused_all, 256, 0)
          == hipSuccess && nb > 0) {
    int grid = nb * 256;                 // 256 CUs on MI355X
    if (grid > 4096) grid = 4096;
    FusedArgs fa;
    fa.query = query; fa.value = value; fa.ref = ref;
    fa.Woff = W_off; fa.boff = b_off; fa.Wattn = W_attn; fa.battn = b_attn;
    fa.Wv = W_v; fa.bv = b_v; fa.Wout = W_out; fa.bout = b_out;
    fa.ws_wv = ws_wv; fa.ws_wol = ws_wol; fa.ws_wout = ws_wout;
    fa.ws_biasf = ws_biasf; fa.ws_val = ws_val; fa.ws_interm = ws_interm;
    fa.ws_offlog = ws_offlog; fa.out = out;
    void* kargs[] = { (void*)&fa };
    if (hipLaunchCooperativeKernel((const void*)fused_all, dim3(grid), blk,
                                   kargs, 0, stream) == hipSuccess)
      coop_done = true;
  }

  // ---- fallback: the proven 4-kernel pipeline (r9) ----
  if (!coop_done) {
    prep_weights<<<dim3(896), blk, 0, stream>>>(W_v, W_out, W_off, W_attn, b_off, b_attn,
                                                ws_wv, ws_wout, ws_wol, ws_biasf);
    gemm_in<<<dim3(340, 5), blk, 0, stream>>>(value, query, ws_wv, ws_wol, b_v, ws_biasf,
                                              ws_val, ws_offlog);
    msda_sample<<<dim3(10880), blk, 0, stream>>>(ws_val, ws_offlog, ref, ws_interm);
    gemm_out<<<dim3(340, 2), blk, 0, stream>>>(ws_interm, ws_wout, b_out, out);
  }
}